// Round 1
// baseline (680.559 us; speedup 1.0000x reference)
//
#include <hip/hip_runtime.h>
#include <hip/hip_bf16.h>

// ---------------------------------------------------------------------------
// BlipAttention: x(32,1024,768) -> qkv -> attention -> scramble -> proj
// All-bf16 MFMA pipeline, fp32 accumulation.
// ---------------------------------------------------------------------------

#define TM 128
#define TN 128
#define BK 32

typedef __attribute__((ext_vector_type(8))) short bf16x8;
typedef __attribute__((ext_vector_type(4))) float f32x4;

__device__ __forceinline__ unsigned short f2b(float f) {
  // round-to-nearest-even bf16 (inputs finite)
  unsigned int u = __float_as_uint(f);
  u = u + 0x7fffu + ((u >> 16) & 1u);
  return (unsigned short)(u >> 16);
}
__device__ __forceinline__ float b2f(unsigned short u) {
  return __uint_as_float(((unsigned int)u) << 16);
}

__device__ __forceinline__ void g2l16(const void* g, void* l) {
  __builtin_amdgcn_global_load_lds(
      (const __attribute__((address_space(1))) unsigned int*)g,
      (__attribute__((address_space(3))) unsigned int*)l, 16, 0, 0);
}

// NT GEMM: C[m][n] = sum_k A[m][k] * B[n][k]; A,B bf16 row-major (K contig).
// EPI 0: bf16 out (per-batch), *scale
// EPI 1: QKV split: bias add, write Q/K/V bf16 (row stride 768), single batch
// EPI 2: fp32 out + bias
template <int EPI>
__global__ __launch_bounds__(256) void gemm_nt(
    const unsigned short* __restrict__ A, const unsigned short* __restrict__ B,
    unsigned short* __restrict__ Cb, unsigned short* __restrict__ Ck,
    unsigned short* __restrict__ Cv, float* __restrict__ Cf,
    const float* __restrict__ bias, int K, int lda, int ldb, int ldc,
    long bsA, long bsB, long bsC, float scale) {
  __shared__ unsigned short As[TM * BK];  // 8 KB
  __shared__ unsigned short Bs[TN * BK];  // 8 KB

  const int bz = blockIdx.z;
  const unsigned short* Ag = A + (long)bz * bsA + (long)(blockIdx.y * TM) * lda;
  const unsigned short* Bg = B + (long)bz * bsB + (long)(blockIdx.x * TN) * ldb;

  const int tid = threadIdx.x;
  const int wave = tid >> 6;
  const int lane = tid & 63;
  const int l15 = lane & 15;
  const int quad = lane >> 4;
  const int wm = (wave & 1) << 6;
  const int wn = (wave >> 1) << 6;

  f32x4 acc[4][4];
#pragma unroll
  for (int i = 0; i < 4; ++i)
#pragma unroll
    for (int j = 0; j < 4; ++j) acc[i][j] = (f32x4){0.f, 0.f, 0.f, 0.f};

  const int srow0 = (wave << 5) + (lane >> 2);  // + i*16
  const int scol = (lane & 3) << 3;             // element offset within row

  for (int k0 = 0; k0 < K; k0 += BK) {
#pragma unroll
    for (int i = 0; i < 2; ++i) {
      const int r = srow0 + (i << 4);
      g2l16(Ag + (long)r * lda + (k0 + scol), &As[(wave << 10) + (i << 9)]);
      g2l16(Bg + (long)r * ldb + (k0 + scol), &Bs[(wave << 10) + (i << 9)]);
    }
    __syncthreads();
    bf16x8 af[4], bfr[4];
#pragma unroll
    for (int i = 0; i < 4; ++i) {
      af[i] = *(const bf16x8*)&As[(wm + i * 16 + l15) * BK + (quad << 3)];
      bfr[i] = *(const bf16x8*)&Bs[(wn + i * 16 + l15) * BK + (quad << 3)];
    }
#pragma unroll
    for (int i = 0; i < 4; ++i)
#pragma unroll
      for (int j = 0; j < 4; ++j)
        acc[i][j] = __builtin_amdgcn_mfma_f32_16x16x32_bf16(af[i], bfr[j],
                                                            acc[i][j], 0, 0, 0);
    __syncthreads();
  }

  // C/D layout: col = lane&15, row = quad*4 + reg (m89/m91-verified)
  const int row0 = blockIdx.y * TM + wm + quad * 4;
  const int col0 = blockIdx.x * TN + wn;
#pragma unroll
  for (int i = 0; i < 4; ++i) {
    const int rowb = row0 + i * 16;
#pragma unroll
    for (int j = 0; j < 4; ++j) {
      const int col = col0 + j * 16 + l15;
      float bv = 0.f;
      if constexpr (EPI != 0) bv = bias[col];
#pragma unroll
      for (int r = 0; r < 4; ++r) {
        const float v = acc[i][j][r];
        const long rr = rowb + r;
        if constexpr (EPI == 0) {
          unsigned short* C = Cb + (long)bz * bsC;
          C[rr * ldc + col] = f2b(v * scale);
        } else if constexpr (EPI == 1) {
          const float q = v + bv;
          const int seg = (col >= 1536) ? 2 : ((col >= 768) ? 1 : 0);
          const int cl = col - seg * 768;
          unsigned short* O = (seg == 0) ? Cb : ((seg == 1) ? Ck : Cv);
          O[rr * 768 + cl] = f2b(q);
        } else {
          Cf[rr * ldc + col] = v + bv;
        }
      }
    }
  }
}

// fp32 -> bf16 elementwise (x), vectorized
__global__ __launch_bounds__(256) void cvt_x(const float4* __restrict__ x,
                                             ushort4* __restrict__ y, long n4) {
  const long i = (long)blockIdx.x * 256 + threadIdx.x;
  if (i < n4) {
    float4 f = x[i];
    ushort4 o;
    o.x = f2b(f.x); o.y = f2b(f.y); o.z = f2b(f.z); o.w = f2b(f.w);
    y[i] = o;
  }
}

// W[RxC] fp32 -> Wt[CxR] bf16 (coalesced writes; small tensors)
__global__ __launch_bounds__(256) void tcvt(const float* __restrict__ W,
                                            unsigned short* __restrict__ Wt,
                                            int R, int C) {
  const long i = (long)blockIdx.x * 256 + threadIdx.x;
  if (i < (long)R * C) {
    const int k = (int)(i % R);
    const int j = (int)(i / R);
    Wt[i] = f2b(W[(long)k * C + j]);
  }
}

// per-batch V[1024][768] -> Vt[768][1024], bf16, 64x64 LDS tiles
__global__ __launch_bounds__(256) void transpose_v(
    const unsigned short* __restrict__ V, unsigned short* __restrict__ Vt) {
  __shared__ unsigned short T[64][72];
  const int b = blockIdx.z;
  const int d0 = blockIdx.x << 6;  // 12 tiles over 768
  const int m0 = blockIdx.y << 6;  // 16 tiles over 1024
  const unsigned short* Vb = V + (long)b * 786432;
  unsigned short* Vtb = Vt + (long)b * 786432;
  const int tid = threadIdx.x;
  const int r = tid >> 2;
  const int c4 = tid & 3;
#pragma unroll
  for (int h = 0; h < 2; ++h) {
    const int cc = (c4 + (h << 2)) << 3;
    *(uint4*)&T[r][cc] = *(const uint4*)&Vb[(long)(m0 + r) * 768 + d0 + cc];
  }
  __syncthreads();
#pragma unroll
  for (int h = 0; h < 2; ++h) {
    const int mm = (c4 + (h << 2)) << 3;
    alignas(16) unsigned short tmp[8];
#pragma unroll
    for (int e = 0; e < 8; ++e) tmp[e] = T[mm + e][r];
    *(uint4*)&Vtb[(long)(d0 + r) * 1024 + m0 + mm] = *(uint4*)tmp;
  }
}

// softmax over rows of 1024 (in place, bf16)
__global__ __launch_bounds__(256) void softmax_rows(
    unsigned short* __restrict__ S) {
  const long row = blockIdx.x;
  unsigned short* p = S + (row << 10);
  const int tid = threadIdx.x;
  const int wave = tid >> 6, lane = tid & 63;
  ushort4 u = *(const ushort4*)&p[tid << 2];
  const float v0 = b2f(u.x), v1 = b2f(u.y), v2 = b2f(u.z), v3 = b2f(u.w);
  float m = fmaxf(fmaxf(v0, v1), fmaxf(v2, v3));
#pragma unroll
  for (int off = 32; off > 0; off >>= 1) m = fmaxf(m, __shfl_xor(m, off));
  __shared__ float smax[4];
  __shared__ float ssum[4];
  if (lane == 0) smax[wave] = m;
  __syncthreads();
  m = fmaxf(fmaxf(smax[0], smax[1]), fmaxf(smax[2], smax[3]));
  const float e0 = __expf(v0 - m), e1 = __expf(v1 - m), e2 = __expf(v2 - m),
              e3 = __expf(v3 - m);
  float s = e0 + e1 + e2 + e3;
#pragma unroll
  for (int off = 32; off > 0; off >>= 1) s += __shfl_xor(s, off);
  if (lane == 0) ssum[wave] = s;
  __syncthreads();
  s = ssum[0] + ssum[1] + ssum[2] + ssum[3];
  const float inv = 1.f / s;
  ushort4 o;
  o.x = f2b(e0 * inv); o.y = f2b(e1 * inv);
  o.z = f2b(e2 * inv); o.w = f2b(e3 * inv);
  *(ushort4*)&p[tid << 2] = o;
}

extern "C" void kernel_launch(void* const* d_in, const int* in_sizes, int n_in,
                              void* d_out, int out_size, void* d_ws,
                              size_t ws_size, hipStream_t stream) {
  const float* x = (const float*)d_in[0];
  const float* qkv_w = (const float*)d_in[1];
  const float* qkv_b = (const float*)d_in[2];
  const float* proj_w = (const float*)d_in[3];
  const float* proj_b = (const float*)d_in[4];
  float* out = (float*)d_out;

  // ws layout (bytes):
  //   0         : x_bf   50331648   (reused as Vt after G1)
  //   50331648  : Wqkv_t  3538944
  //   53870592  : Wp_t    1179648
  //   55050240  : Q      50331648   (reused as hbuf after G2)
  //   105381888 : K      50331648
  //   155713536 : V      50331648
  //   206045184 : S      67108864   -> total 273154048
  char* ws = (char*)d_ws;
  unsigned short* x_bf = (unsigned short*)ws;
  unsigned short* Wqkv = (unsigned short*)(ws + 50331648);
  unsigned short* Wp = (unsigned short*)(ws + 53870592);
  unsigned short* Qb = (unsigned short*)(ws + 55050240);
  unsigned short* Kb = (unsigned short*)(ws + 105381888);
  unsigned short* Vb = (unsigned short*)(ws + 155713536);
  unsigned short* Sb = (unsigned short*)(ws + 206045184);
  unsigned short* Vt = x_bf;  // x_bf dead after G1
  unsigned short* Hb = Qb;    // Q dead after G2

  // 1) convert inputs to bf16 (weights also transposed to [n][k])
  cvt_x<<<24576, 256, 0, stream>>>((const float4*)x, (ushort4*)x_bf, 6291456);
  tcvt<<<(1769472 + 255) / 256, 256, 0, stream>>>(qkv_w, Wqkv, 768, 2304);
  tcvt<<<(589824 + 255) / 256, 256, 0, stream>>>(proj_w, Wp, 768, 768);

  // 2) QKV GEMM: [32768x768] x [2304x768]^T + bias -> Q,K,V bf16
  gemm_nt<1><<<dim3(18, 256, 1), 256, 0, stream>>>(
      x_bf, Wqkv, Qb, Kb, Vb, nullptr, qkv_b, 768, 768, 768, 0, 0, 0, 0, 1.f);

  // 3) V -> V^T per batch
  transpose_v<<<dim3(12, 16, 32), 256, 0, stream>>>(Vb, Vt);

  // 4) scores: S[b] = Q[b] K[b]^T * 1/sqrt(768), bf16
  gemm_nt<0><<<dim3(8, 8, 32), 256, 0, stream>>>(
      Qb, Kb, Sb, nullptr, nullptr, nullptr, nullptr, 768, 768, 768, 1024,
      786432, 786432, 1048576, 0.03608439182435161f);

  // 5) softmax rows (in place)
  softmax_rows<<<32768, 256, 0, stream>>>(Sb);

  // 6) O^T: hbuf[b][d][n] = sum_m Vt[b][d][m] * P[b][n][m]  (scramble = free)
  gemm_nt<0><<<dim3(8, 6, 32), 256, 0, stream>>>(
      Vt, Sb, Hb, nullptr, nullptr, nullptr, nullptr, 1024, 1024, 1024, 1024,
      786432, 1048576, 786432, 1.f);

  // 7) proj: out[32768x768] = hbuf(reinterp 32768x768) x Wp^T + bias, fp32
  gemm_nt<2><<<dim3(6, 256, 1), 256, 0, stream>>>(
      Hb, Wp, nullptr, nullptr, nullptr, out, proj_b, 768, 768, 768, 768, 0, 0,
      0, 1.f);
}

// Round 2
// 615.028 us; speedup vs baseline: 1.1066x; 1.1066x over previous
//
#include <hip/hip_runtime.h>
#include <hip/hip_bf16.h>

// ---------------------------------------------------------------------------
// BlipAttention: x(32,1024,768) -> qkv -> attention -> scramble -> proj
// All-bf16 MFMA pipeline, fp32 accumulation.
// R2: BK=64 with XOR-swizzled LDS (halves barrier count, <=2-way bank
//     conflicts); softmax fused into G2/G4 epilogues (E=exp, atomic row sums,
//     1/Z column scaling in PV epilogue).
// ---------------------------------------------------------------------------

#define TM 128
#define TN 128
#define BK 64

typedef __attribute__((ext_vector_type(8))) short bf16x8;
typedef __attribute__((ext_vector_type(4))) float f32x4;

__device__ __forceinline__ unsigned short f2b(float f) {
  unsigned int u = __float_as_uint(f);
  u = u + 0x7fffu + ((u >> 16) & 1u);
  return (unsigned short)(u >> 16);
}
__device__ __forceinline__ float b2f(unsigned short u) {
  return __uint_as_float(((unsigned int)u) << 16);
}

__device__ __forceinline__ void g2l16(const void* g, void* l) {
  __builtin_amdgcn_global_load_lds(
      (const __attribute__((address_space(1))) unsigned int*)g,
      (__attribute__((address_space(3))) unsigned int*)l, 16, 0, 0);
}

// NT GEMM: C[m][n] = sum_k A[m][k] * B[n][k]; A,B bf16 row-major (K contig).
// EPI 1: QKV split: bias add, write Q/K/V bf16 (row stride 768), single batch
// EPI 2: fp32 out + bias
// EPI 3: E = exp(v*scale) bf16 out + atomic row-sum accumulation into Z
// EPI 4: bf16 out = v * (1/Z[col])
template <int EPI>
__global__ __launch_bounds__(256) void gemm_nt(
    const unsigned short* __restrict__ A, const unsigned short* __restrict__ B,
    unsigned short* __restrict__ Cb, unsigned short* __restrict__ Ck,
    unsigned short* __restrict__ Cv, float* __restrict__ Cf,
    const float* __restrict__ bias, float* __restrict__ Z, int K, int lda,
    int ldb, int ldc, long bsA, long bsB, long bsC, float scale) {
  __shared__ unsigned short As[TM * BK];  // 16 KB
  __shared__ unsigned short Bs[TN * BK];  // 16 KB

  const int bz = blockIdx.z;
  const unsigned short* Ag = A + (long)bz * bsA + (long)(blockIdx.y * TM) * lda;
  const unsigned short* Bg = B + (long)bz * bsB + (long)(blockIdx.x * TN) * ldb;

  const int tid = threadIdx.x;
  const int wave = tid >> 6;
  const int lane = tid & 63;
  const int l15 = lane & 15;
  const int quad = lane >> 4;
  const int wm = (wave & 1) << 6;
  const int wn = (wave >> 1) << 6;

  f32x4 acc[4][4];
#pragma unroll
  for (int i = 0; i < 4; ++i)
#pragma unroll
    for (int j = 0; j < 4; ++j) acc[i][j] = (f32x4){0.f, 0.f, 0.f, 0.f};

  // staging: wave covers rows wave*32 .. wave*32+31; 4 issues of 8 rows.
  // lane -> (rowInGroup = lane>>3, slot j = lane&7). Global chunk read is
  // j ^ (row&7) so that LDS slot s of row r holds global chunk s ^ (r&7).
  const int sj = lane & 7;
  const int srow_in = lane >> 3;

  for (int k0 = 0; k0 < K; k0 += BK) {
#pragma unroll
    for (int i = 0; i < 4; ++i) {
      const int r = (wave << 5) + (i << 3) + srow_in;
      const int cg = (sj ^ (r & 7)) << 3;  // element offset of global chunk
      g2l16(Ag + (long)r * lda + (k0 + cg), &As[(wave << 11) + (i << 9)]);
      g2l16(Bg + (long)r * ldb + (k0 + cg), &Bs[(wave << 11) + (i << 9)]);
    }
    __syncthreads();
#pragma unroll
    for (int kk = 0; kk < 2; ++kk) {
      bf16x8 af[4], bfr[4];
#pragma unroll
      for (int i = 0; i < 4; ++i) {
        const int ra = wm + i * 16 + l15;
        const int rb = wn + i * 16 + l15;
        const int c = quad + (kk << 2);
        af[i] = *(const bf16x8*)&As[(ra << 6) + ((c ^ (ra & 7)) << 3)];
        bfr[i] = *(const bf16x8*)&Bs[(rb << 6) + ((c ^ (rb & 7)) << 3)];
      }
#pragma unroll
      for (int i = 0; i < 4; ++i)
#pragma unroll
        for (int j = 0; j < 4; ++j)
          acc[i][j] = __builtin_amdgcn_mfma_f32_16x16x32_bf16(
              af[i], bfr[j], acc[i][j], 0, 0, 0);
    }
    __syncthreads();
  }

  // C/D layout: col = lane&15, row = quad*4 + reg (m89/m91-verified)
  const int row0 = blockIdx.y * TM + wm + quad * 4;
  const int col0 = blockIdx.x * TN + wn;
#pragma unroll
  for (int i = 0; i < 4; ++i) {
    const int rowb = row0 + i * 16;
#pragma unroll
    for (int j = 0; j < 4; ++j) {
      const int col = col0 + j * 16 + l15;
      float bv = 0.f;
      if constexpr (EPI == 1 || EPI == 2) bv = bias[col];
      float zinv = 1.f;
      if constexpr (EPI == 4) zinv = 1.f / Z[(long)bz * 1024 + col];
      float esum[4];
#pragma unroll
      for (int r = 0; r < 4; ++r) {
        const float v = acc[i][j][r];
        const long rr = rowb + r;
        if constexpr (EPI == 1) {
          const float q = v + bv;
          const int seg = (col >= 1536) ? 2 : ((col >= 768) ? 1 : 0);
          const int cl = col - seg * 768;
          unsigned short* O = (seg == 0) ? Cb : ((seg == 1) ? Ck : Cv);
          O[rr * 768 + cl] = f2b(q);
        } else if constexpr (EPI == 2) {
          Cf[rr * ldc + col] = v + bv;
        } else if constexpr (EPI == 3) {
          const float e = __expf(v * scale);
          esum[r] = e;
          unsigned short* C = Cb + (long)bz * bsC;
          C[rr * ldc + col] = f2b(e);
        } else {  // EPI 4
          unsigned short* C = Cb + (long)bz * bsC;
          C[rr * ldc + col] = f2b(v * zinv);
        }
      }
      if constexpr (EPI == 3) {
        // accumulate per-row sums across the 16 column-lanes of this quad
#pragma unroll
        for (int r = 0; r < 4; ++r) {
          float s = esum[r];
          s += __shfl_xor(s, 1);
          s += __shfl_xor(s, 2);
          s += __shfl_xor(s, 4);
          s += __shfl_xor(s, 8);
          if (l15 == 0) atomicAdd(&Z[(long)bz * 1024 + rowb + r], s);
        }
      }
    }
  }
}

// fp32 -> bf16 elementwise (x), vectorized
__global__ __launch_bounds__(256) void cvt_x(const float4* __restrict__ x,
                                             ushort4* __restrict__ y, long n4) {
  const long i = (long)blockIdx.x * 256 + threadIdx.x;
  if (i < n4) {
    float4 f = x[i];
    ushort4 o;
    o.x = f2b(f.x); o.y = f2b(f.y); o.z = f2b(f.z); o.w = f2b(f.w);
    y[i] = o;
  }
}

// W[RxC] fp32 -> Wt[CxR] bf16 (coalesced writes; small tensors)
__global__ __launch_bounds__(256) void tcvt(const float* __restrict__ W,
                                            unsigned short* __restrict__ Wt,
                                            int R, int C) {
  const long i = (long)blockIdx.x * 256 + threadIdx.x;
  if (i < (long)R * C) {
    const int k = (int)(i % R);
    const int j = (int)(i / R);
    Wt[i] = f2b(W[(long)k * C + j]);
  }
}

// per-batch V[1024][768] -> Vt[768][1024], bf16, 64x64 LDS tiles
__global__ __launch_bounds__(256) void transpose_v(
    const unsigned short* __restrict__ V, unsigned short* __restrict__ Vt) {
  __shared__ unsigned short T[64][72];
  const int b = blockIdx.z;
  const int d0 = blockIdx.x << 6;
  const int m0 = blockIdx.y << 6;
  const unsigned short* Vb = V + (long)b * 786432;
  unsigned short* Vtb = Vt + (long)b * 786432;
  const int tid = threadIdx.x;
  const int r = tid >> 2;
  const int c4 = tid & 3;
#pragma unroll
  for (int h = 0; h < 2; ++h) {
    const int cc = (c4 + (h << 2)) << 3;
    *(uint4*)&T[r][cc] = *(const uint4*)&Vb[(long)(m0 + r) * 768 + d0 + cc];
  }
  __syncthreads();
#pragma unroll
  for (int h = 0; h < 2; ++h) {
    const int mm = (c4 + (h << 2)) << 3;
    alignas(16) unsigned short tmp[8];
#pragma unroll
    for (int e = 0; e < 8; ++e) tmp[e] = T[mm + e][r];
    *(uint4*)&Vtb[(long)(d0 + r) * 1024 + m0 + mm] = *(uint4*)tmp;
  }
}

extern "C" void kernel_launch(void* const* d_in, const int* in_sizes, int n_in,
                              void* d_out, int out_size, void* d_ws,
                              size_t ws_size, hipStream_t stream) {
  const float* x = (const float*)d_in[0];
  const float* qkv_w = (const float*)d_in[1];
  const float* qkv_b = (const float*)d_in[2];
  const float* proj_w = (const float*)d_in[3];
  const float* proj_b = (const float*)d_in[4];
  float* out = (float*)d_out;

  // ws layout (bytes):
  //   0         : x_bf   50331648   (reused as Vt after G1)
  //   50331648  : Wqkv_t  3538944
  //   53870592  : Wp_t    1179648
  //   55050240  : Q      50331648   (reused as hbuf after G2)
  //   105381888 : K      50331648
  //   155713536 : V      50331648   (head reused as Z[32][1024] f32 after T)
  //   206045184 : E      67108864   -> total 273154048
  char* ws = (char*)d_ws;
  unsigned short* x_bf = (unsigned short*)ws;
  unsigned short* Wqkv = (unsigned short*)(ws + 50331648);
  unsigned short* Wp = (unsigned short*)(ws + 53870592);
  unsigned short* Qb = (unsigned short*)(ws + 55050240);
  unsigned short* Kb = (unsigned short*)(ws + 105381888);
  unsigned short* Vb = (unsigned short*)(ws + 155713536);
  unsigned short* Sb = (unsigned short*)(ws + 206045184);
  unsigned short* Vt = x_bf;          // x_bf dead after G1
  unsigned short* Hb = Qb;            // Q dead after G2
  float* Zs = (float*)Vb;             // V dead after transpose_v

  // 1) convert inputs to bf16 (weights also transposed to [n][k])
  cvt_x<<<24576, 256, 0, stream>>>((const float4*)x, (ushort4*)x_bf, 6291456);
  tcvt<<<(1769472 + 255) / 256, 256, 0, stream>>>(qkv_w, Wqkv, 768, 2304);
  tcvt<<<(589824 + 255) / 256, 256, 0, stream>>>(proj_w, Wp, 768, 768);

  // 2) QKV GEMM: [32768x768] x [2304x768]^T + bias -> Q,K,V bf16
  gemm_nt<1><<<dim3(18, 256, 1), 256, 0, stream>>>(
      x_bf, Wqkv, Qb, Kb, Vb, nullptr, qkv_b, nullptr, 768, 768, 768, 0, 0, 0,
      0, 1.f);

  // 3) V -> V^T per batch
  transpose_v<<<dim3(12, 16, 32), 256, 0, stream>>>(Vb, Vt);

  // 3b) zero the softmax row-sum accumulator (V region is now dead)
  hipMemsetAsync(Zs, 0, 32 * 1024 * sizeof(float), stream);

  // 4) E[b] = exp(Q[b] K[b]^T / sqrt(768)) bf16 + row sums into Zs
  gemm_nt<3><<<dim3(8, 8, 32), 256, 0, stream>>>(
      Qb, Kb, Sb, nullptr, nullptr, nullptr, nullptr, Zs, 768, 768, 768, 1024,
      786432, 786432, 1048576, 0.03608439182435161f);

  // 5) O^T: hbuf[b][d][n] = (sum_m Vt[b][d][m] E[b][n][m]) / Z[b][n]
  gemm_nt<4><<<dim3(8, 6, 32), 256, 0, stream>>>(
      Vt, Sb, Hb, nullptr, nullptr, nullptr, nullptr, Zs, 1024, 1024, 1024,
      1024, 786432, 1048576, 786432, 1.f);

  // 6) proj: out[32768x768] = hbuf x Wp^T + bias, fp32
  gemm_nt<2><<<dim3(6, 256, 1), 256, 0, stream>>>(
      Hb, Wp, nullptr, nullptr, nullptr, out, proj_b, nullptr, 768, 768, 768,
      768, 0, 0, 0, 1.f);
}

// Round 3
// 612.378 us; speedup vs baseline: 1.1113x; 1.0043x over previous
//
#include <hip/hip_runtime.h>
#include <hip/hip_bf16.h>

// ---------------------------------------------------------------------------
// BlipAttention: x(32,1024,768) -> qkv -> attention -> scramble -> proj
// All-bf16 MFMA pipeline, fp32 accumulation.
// R2: BK=64 + XOR-swizzled LDS (0 bank conflicts); softmax fused into G2/G4.
// R3: 32x32x16 MFMA (2382 TF ceiling vs 2075; 16 ops/iter/wave vs 32).
//     Wave = 64x64 out = 2x2 tiles of 32x32, 16-float acc each.
// ---------------------------------------------------------------------------

#define TM 128
#define TN 128
#define BK 64

typedef __attribute__((ext_vector_type(8))) short bf16x8;
typedef __attribute__((ext_vector_type(16))) float f32x16;

__device__ __forceinline__ unsigned short f2b(float f) {
  unsigned int u = __float_as_uint(f);
  u = u + 0x7fffu + ((u >> 16) & 1u);
  return (unsigned short)(u >> 16);
}

__device__ __forceinline__ void g2l16(const void* g, void* l) {
  __builtin_amdgcn_global_load_lds(
      (const __attribute__((address_space(1))) unsigned int*)g,
      (__attribute__((address_space(3))) unsigned int*)l, 16, 0, 0);
}

// NT GEMM: C[m][n] = sum_k A[m][k] * B[n][k]; A,B bf16 row-major (K contig).
// EPI 1: QKV split: bias add, write Q/K/V bf16 (seg = blockIdx.x/6)
// EPI 2: fp32 out + bias
// EPI 3: E = exp(v*scale) bf16 out + atomic row-sum accumulation into Z
// EPI 4: bf16 out = v * (1/Z[col])
template <int EPI>
__global__ __launch_bounds__(256) void gemm_nt(
    const unsigned short* __restrict__ A, const unsigned short* __restrict__ B,
    unsigned short* __restrict__ Cb, unsigned short* __restrict__ Ck,
    unsigned short* __restrict__ Cv, float* __restrict__ Cf,
    const float* __restrict__ bias, float* __restrict__ Z, int K, int lda,
    int ldb, int ldc, long bsA, long bsB, long bsC, float scale) {
  __shared__ unsigned short As[TM * BK];  // 16 KB
  __shared__ unsigned short Bs[TN * BK];  // 16 KB

  const int bz = blockIdx.z;
  const unsigned short* Ag = A + (long)bz * bsA + (long)(blockIdx.y * TM) * lda;
  const unsigned short* Bg = B + (long)bz * bsB + (long)(blockIdx.x * TN) * ldb;

  const int tid = threadIdx.x;
  const int wave = tid >> 6;
  const int lane = tid & 63;
  const int l31 = lane & 31;
  const int hi = lane >> 5;
  const int wm = (wave & 1) << 6;
  const int wn = (wave >> 1) << 6;

  f32x16 acc[2][2];
#pragma unroll
  for (int mt = 0; mt < 2; ++mt)
#pragma unroll
    for (int nt = 0; nt < 2; ++nt)
#pragma unroll
      for (int p = 0; p < 16; ++p) acc[mt][nt][p] = 0.f;

  // staging: wave covers rows wave*32 .. wave*32+31; 4 issues of 8 rows.
  // LDS slot s of row r holds global 8-elem chunk (s ^ (r&7)).
  const int sj = lane & 7;
  const int srow_in = lane >> 3;

  for (int k0 = 0; k0 < K; k0 += BK) {
#pragma unroll
    for (int i = 0; i < 4; ++i) {
      const int r = (wave << 5) + (i << 3) + srow_in;
      const int cg = (sj ^ (r & 7)) << 3;
      g2l16(Ag + (long)r * lda + (k0 + cg), &As[(wave << 11) + (i << 9)]);
      g2l16(Bg + (long)r * ldb + (k0 + cg), &Bs[(wave << 11) + (i << 9)]);
    }
    __syncthreads();
    // fragment: lane holds op[m = l31][k = hi*8 + j]; K-slice s covers
    // elements s*16 .. s*16+15 -> chunk index s*2 + hi.
#pragma unroll
    for (int s = 0; s < 4; ++s) {
      bf16x8 af[2], bfr[2];
#pragma unroll
      for (int t = 0; t < 2; ++t) {
        const int ra = wm + t * 32 + l31;
        const int rb = wn + t * 32 + l31;
        const int c = s * 2 + hi;
        af[t] = *(const bf16x8*)&As[(ra << 6) + ((c ^ (ra & 7)) << 3)];
        bfr[t] = *(const bf16x8*)&Bs[(rb << 6) + ((c ^ (rb & 7)) << 3)];
      }
#pragma unroll
      for (int mt = 0; mt < 2; ++mt)
#pragma unroll
        for (int nt = 0; nt < 2; ++nt)
          acc[mt][nt] = __builtin_amdgcn_mfma_f32_32x32x16_bf16(
              af[mt], bfr[nt], acc[mt][nt], 0, 0, 0);
    }
    __syncthreads();
  }

  // C/D layout (m74/m101): col = lane&31, row = (p&3) + 8*(p>>2) + 4*hi
  const int row0 = blockIdx.y * TM + wm + 4 * hi;
  const int col0 = blockIdx.x * TN + wn;
  float esum[2][16];  // EPI 3 only: per (mt, p) row sums across both nt
#pragma unroll
  for (int mt = 0; mt < 2; ++mt) {
#pragma unroll
    for (int nt = 0; nt < 2; ++nt) {
      const int col = col0 + nt * 32 + l31;
      float bv = 0.f;
      if constexpr (EPI == 1 || EPI == 2) bv = bias[col];
      float zinv = 1.f;
      if constexpr (EPI == 4) zinv = 1.f / Z[(long)bz * 1024 + col];
#pragma unroll
      for (int p = 0; p < 16; ++p) {
        const float v = acc[mt][nt][p];
        const long rr = row0 + mt * 32 + (p & 3) + ((p >> 2) << 3);
        if constexpr (EPI == 1) {
          const int seg = blockIdx.x / 6;  // 0:Q 1:K 2:V (TN=128 divides 768)
          const int cl = col - seg * 768;
          unsigned short* O = (seg == 0) ? Cb : ((seg == 1) ? Ck : Cv);
          O[rr * 768 + cl] = f2b(v + bv);
        } else if constexpr (EPI == 2) {
          Cf[rr * ldc + col] = v + bv;
        } else if constexpr (EPI == 3) {
          const float e = __expf(v * scale);
          if (nt == 0)
            esum[mt][p] = e;
          else
            esum[mt][p] += e;
          unsigned short* C = Cb + (long)bz * bsC;
          C[rr * ldc + col] = f2b(e);
        } else {  // EPI 4
          unsigned short* C = Cb + (long)bz * bsC;
          C[rr * ldc + col] = f2b(v * zinv);
        }
      }
    }
    if constexpr (EPI == 3) {
#pragma unroll
      for (int p = 0; p < 16; ++p) {
        float s = esum[mt][p];
        s += __shfl_xor(s, 1);
        s += __shfl_xor(s, 2);
        s += __shfl_xor(s, 4);
        s += __shfl_xor(s, 8);
        s += __shfl_xor(s, 16);
        if (l31 == 0) {
          const long rr = row0 + mt * 32 + (p & 3) + ((p >> 2) << 3);
          atomicAdd(&Z[(long)bz * 1024 + rr], s);
        }
      }
    }
  }
}

// fp32 -> bf16 elementwise (x), vectorized
__global__ __launch_bounds__(256) void cvt_x(const float4* __restrict__ x,
                                             ushort4* __restrict__ y, long n4) {
  const long i = (long)blockIdx.x * 256 + threadIdx.x;
  if (i < n4) {
    float4 f = x[i];
    ushort4 o;
    o.x = f2b(f.x); o.y = f2b(f.y); o.z = f2b(f.z); o.w = f2b(f.w);
    y[i] = o;
  }
}

// W[RxC] fp32 -> Wt[CxR] bf16 (coalesced writes; small tensors)
__global__ __launch_bounds__(256) void tcvt(const float* __restrict__ W,
                                            unsigned short* __restrict__ Wt,
                                            int R, int C) {
  const long i = (long)blockIdx.x * 256 + threadIdx.x;
  if (i < (long)R * C) {
    const int k = (int)(i % R);
    const int j = (int)(i / R);
    Wt[i] = f2b(W[(long)k * C + j]);
  }
}

// per-batch V[1024][768] -> Vt[768][1024], bf16, 64x64 LDS tiles
__global__ __launch_bounds__(256) void transpose_v(
    const unsigned short* __restrict__ V, unsigned short* __restrict__ Vt) {
  __shared__ unsigned short T[64][72];
  const int b = blockIdx.z;
  const int d0 = blockIdx.x << 6;
  const int m0 = blockIdx.y << 6;
  const unsigned short* Vb = V + (long)b * 786432;
  unsigned short* Vtb = Vt + (long)b * 786432;
  const int tid = threadIdx.x;
  const int r = tid >> 2;
  const int c4 = tid & 3;
#pragma unroll
  for (int h = 0; h < 2; ++h) {
    const int cc = (c4 + (h << 2)) << 3;
    *(uint4*)&T[r][cc] = *(const uint4*)&Vb[(long)(m0 + r) * 768 + d0 + cc];
  }
  __syncthreads();
#pragma unroll
  for (int h = 0; h < 2; ++h) {
    const int mm = (c4 + (h << 2)) << 3;
    alignas(16) unsigned short tmp[8];
#pragma unroll
    for (int e = 0; e < 8; ++e) tmp[e] = T[mm + e][r];
    *(uint4*)&Vtb[(long)(d0 + r) * 1024 + m0 + mm] = *(uint4*)tmp;
  }
}

extern "C" void kernel_launch(void* const* d_in, const int* in_sizes, int n_in,
                              void* d_out, int out_size, void* d_ws,
                              size_t ws_size, hipStream_t stream) {
  const float* x = (const float*)d_in[0];
  const float* qkv_w = (const float*)d_in[1];
  const float* qkv_b = (const float*)d_in[2];
  const float* proj_w = (const float*)d_in[3];
  const float* proj_b = (const float*)d_in[4];
  float* out = (float*)d_out;

  char* ws = (char*)d_ws;
  unsigned short* x_bf = (unsigned short*)ws;
  unsigned short* Wqkv = (unsigned short*)(ws + 50331648);
  unsigned short* Wp = (unsigned short*)(ws + 53870592);
  unsigned short* Qb = (unsigned short*)(ws + 55050240);
  unsigned short* Kb = (unsigned short*)(ws + 105381888);
  unsigned short* Vb = (unsigned short*)(ws + 155713536);
  unsigned short* Sb = (unsigned short*)(ws + 206045184);
  unsigned short* Vt = x_bf;  // x_bf dead after G1
  unsigned short* Hb = Qb;    // Q dead after G2
  float* Zs = (float*)Vb;     // V dead after transpose_v

  // 1) convert inputs to bf16 (weights also transposed to [n][k])
  cvt_x<<<24576, 256, 0, stream>>>((const float4*)x, (ushort4*)x_bf, 6291456);
  tcvt<<<(1769472 + 255) / 256, 256, 0, stream>>>(qkv_w, Wqkv, 768, 2304);
  tcvt<<<(589824 + 255) / 256, 256, 0, stream>>>(proj_w, Wp, 768, 768);

  // 2) QKV GEMM: [32768x768] x [2304x768]^T + bias -> Q,K,V bf16
  gemm_nt<1><<<dim3(18, 256, 1), 256, 0, stream>>>(
      x_bf, Wqkv, Qb, Kb, Vb, nullptr, qkv_b, nullptr, 768, 768, 768, 0, 0, 0,
      0, 1.f);

  // 3) V -> V^T per batch
  transpose_v<<<dim3(12, 16, 32), 256, 0, stream>>>(Vb, Vt);

  // 3b) zero the softmax row-sum accumulator (V region is now dead)
  hipMemsetAsync(Zs, 0, 32 * 1024 * sizeof(float), stream);

  // 4) E[b] = exp(Q[b] K[b]^T / sqrt(768)) bf16 + row sums into Zs
  gemm_nt<3><<<dim3(8, 8, 32), 256, 0, stream>>>(
      Qb, Kb, Sb, nullptr, nullptr, nullptr, nullptr, Zs, 768, 768, 768, 1024,
      786432, 786432, 1048576, 0.03608439182435161f);

  // 5) O^T: hbuf[b][d][n] = (sum_m Vt[b][d][m] E[b][n][m]) / Z[b][n]
  gemm_nt<4><<<dim3(8, 6, 32), 256, 0, stream>>>(
      Vt, Sb, Hb, nullptr, nullptr, nullptr, nullptr, Zs, 1024, 1024, 1024,
      1024, 786432, 1048576, 786432, 1.f);

  // 6) proj: out[32768x768] = hbuf x Wp^T + bias, fp32
  gemm_nt<2><<<dim3(6, 256, 1), 256, 0, stream>>>(
      Hb, Wp, nullptr, nullptr, nullptr, out, proj_b, nullptr, 768, 768, 768,
      768, 0, 0, 0, 1.f);
}